// Round 11
// baseline (276.054 us; speedup 1.0000x reference)
//
#include <hip/hip_runtime.h>
#include <stdint.h>

// ---------------------------------------------------------------------------
// LocalBranch: ResNetMLP (5x GEMM+LN) + per-graph distance softmax pool.
// R11 = R10 + two fixes driven by the time accounting:
//  (1) prep_weights was 120 blocks (<=1 wave/CU), latency-bound on cold HBM
//      weight reads: ~60 us hidden in every round (total-mlp ~= 83 us const).
//      Now per-element, 960 blocks x 256 thr: coalesced writes, 15 waves/CU.
//  (2) mlp wave retile 2x8 -> 4x4 (wave tile 16x64): A-frag LDS reads halve
//      (1 b128/kc), acc stays 16 regs; B L2 traffic 1->2 GB (still <40% L2).
// ---------------------------------------------------------------------------

typedef __attribute__((ext_vector_type(8))) short bf16x8;   // 8 bf16 = 4 VGPRs
typedef __attribute__((ext_vector_type(4))) float f32x4;

#define XB_STRIDE 264            // bf16 elems; 132 dwords/row
#define YB_STRIDE 260            // fp32; row step == 4 banks
#define ZB_STRIDE 136            // pool Z tile 128+8
#define LDS_YB    33792          // byte offset (Xb = 64*264*2 = 33792)
#define LDS_PAR   100352         // 33792 + 64*260*4 (=66560)
#define LDS_TOTAL 103424         // + 768*4

__device__ __forceinline__ unsigned int rne16(float f) {
  unsigned int u = __builtin_bit_cast(unsigned int, f);
  return u + 0x7fffu + ((u >> 16) & 1u);     // RNE bf16 in high 16 bits
}
__device__ __forceinline__ unsigned short f2bf(float f) {
  return (unsigned short)(rne16(f) >> 16);
}
__device__ __forceinline__ float bf2f(unsigned short h) {
  unsigned int u = ((unsigned int)h) << 16;
  return __builtin_bit_cast(float, u);
}
__device__ __forceinline__ f32x4 zero4() {
  f32x4 v; v.x = 0.f; v.y = 0.f; v.z = 0.f; v.w = 0.f; return v;
}
template <int CTRL>
__device__ __forceinline__ float dpp_add(float v) {
  int p = __builtin_amdgcn_update_dpp(0, __builtin_bit_cast(int, v),
                                      CTRL, 0xF, 0xF, true);
  return v + __builtin_bit_cast(float, p);
}
__device__ __forceinline__ float red16(float v) {  // sum over 16-lane group
  v = dpp_add<0xB1>(v);    // xor1
  v = dpp_add<0x4E>(v);    // xor2
  v = dpp_add<0x141>(v);   // row_half_mirror
  v = dpp_add<0x140>(v);   // row_mirror
  return v;
}

// ---------------------------------------------------------------------------
// Weight prep, per-element for TLP: output elem t = g*8 + e, g = f*64 + lane,
// frag f = kc*(N/16) + ntile; reads W[k][n] with n = ntile*16 + (lane&15),
// k = kc*32 + (lane>>4)*8 + e. Writes ws[t] fully coalesced. 960x256 thr
// (15 waves/CU) hides the cold-HBM read latency (R10 prep: 1 wave/CU, ~60us).
// ws regions (bf16 elems): stem @0 ; blocks @16384,81920,147456 ; head @212992 ;
// Z buffer @262144 (1024*128*128).
// ---------------------------------------------------------------------------
__global__ void prep_weights(const float* __restrict__ Win, const float* __restrict__ Wb,
                             const float* __restrict__ Wout, unsigned short* __restrict__ ws) {
  int t = blockIdx.x * 256 + threadIdx.x;
  if (t >= 245760) return;
  int g = t >> 3, e = t & 7;
  const float* W; int N; int local;
  if (g < 2048) { W = Win; N = 256; local = g; }
  else if (g < 26624) {
    int i = g - 2048; W = Wb + (i >> 13) * 65536; N = 256; local = i & 8191;
  } else { W = Wout; N = 128; local = g - 26624; }
  int f = local >> 6, lane = local & 63;
  int NTL = N >> 4;
  int kc = f / NTL, ntile = f - kc * NTL;
  int n = ntile * 16 + (lane & 15);
  int k = kc * 32 + ((lane >> 4) * 8) + e;
  ws[t] = f2bf(W[(size_t)k * N + n]);
}

// ---------------------------------------------------------------------------
// One GEMM layer over 64 rows, 16 waves = 4 row-groups x 4 col-groups.
// Wave tile 16 x (16*NT); NT=4 for N=256, NT=2 for N=128.
// MODE: 0 stem relu(ln) ; 1 residual (row-domain register carry) ; 2 head ->
// writes z straight to global Z (no Xb store).
// Phase-B column map (swizzled): thread (wave*4+q, cols {l16*4+64j .. +3}).
// ---------------------------------------------------------------------------
template <int KL, int N, int MODE>
__device__ __forceinline__ void layer(unsigned short* __restrict__ Xb,
                                      float* __restrict__ Yb, float* __restrict__ par,
                                      const unsigned short* __restrict__ Wf,
                                      int tid, int wave, int lane,
                                      const float* __restrict__ bias,
                                      const float* __restrict__ gam,
                                      const float* __restrict__ bet,
                                      float (&xprev)[16],
                                      unsigned short* __restrict__ Z, size_t rowglob) {
  constexpr int NT = N / 64;         // frags per wave per k-slab (4 / 2)
  constexpr int NTL = N / 16;        // 16-col tiles across N
  constexpr int KC = KL / 32;        // 32-wide K slabs
  constexpr int J = N / 64;          // 4-col j-groups per thread in phase B
  const int wr = wave >> 2, wc = wave & 3;
  const int q = lane >> 4, l16 = lane & 15;
  const int rowbase = wr * 16;
  const int colbase = wc * 16 * NT;
  const unsigned short* Wl = Wf + lane * 8;

  f32x4 acc[NT];
#pragma unroll
  for (int nt = 0; nt < NT; ++nt) acc[nt] = zero4();

  bf16x8 bcur[NT];
#pragma unroll
  for (int nt = 0; nt < NT; ++nt)    // prefetch slab 0 before the barrier
    bcur[nt] = *reinterpret_cast<const bf16x8*>(Wl + (size_t)(wc * NT + nt) * 512);

  __syncthreads();                   // B1: prev phase-B done (Xb/par reusable)
  // stage params (bias|gamma|beta) -> LDS, read in phase B after B2
  if (tid < 3 * N) {
    float v = (tid < N) ? bias[tid] : (tid < 2 * N) ? gam[tid - N] : bet[tid - 2 * N];
    par[tid] = v;
  }
#pragma unroll
  for (int kc = 0; kc < KC; ++kc) {
    bf16x8 bnext[NT];
    if (kc + 1 < KC) {
#pragma unroll
      for (int nt = 0; nt < NT; ++nt)
        bnext[nt] = *reinterpret_cast<const bf16x8*>(
            Wl + (size_t)((kc + 1) * NTL + wc * NT + nt) * 512);
    }
    const int kk = kc * 32 + q * 8;
    bf16x8 a = *reinterpret_cast<const bf16x8*>(Xb + (rowbase + l16) * XB_STRIDE + kk);
#pragma unroll
    for (int nt = 0; nt < NT; ++nt)
      acc[nt] = __builtin_amdgcn_mfma_f32_16x16x32_bf16(a, bcur[nt], acc[nt], 0, 0, 0);
    if (kc + 1 < KC) {
#pragma unroll
      for (int nt = 0; nt < NT; ++nt) bcur[nt] = bnext[nt];
    }
  }

  // ---- phase A: raw acc -> Yb fp32 (bank residue 16q+4r+l16 : 2-way, free)
#pragma unroll
  for (int nt = 0; nt < NT; ++nt) {
    const int col = colbase + 16 * nt + l16;
#pragma unroll
    for (int r = 0; r < 4; ++r)
      Yb[(rowbase + 4 * q + r) * YB_STRIDE + col] = acc[nt][r];
  }
  __syncthreads();                   // B2: Yb + par complete; K-loop Xb reads done

  // ---- phase B: row-domain LN, swizzled cols {l16*4 + 64j .. +3}
  const int row = wave * 4 + q;
  const int cb = l16 * 4;
  float y[4 * J];
#pragma unroll
  for (int j = 0; j < J; ++j)
    *reinterpret_cast<f32x4*>(y + 4 * j) =
        *reinterpret_cast<const f32x4*>(Yb + row * YB_STRIDE + cb + 64 * j);
  float bv[4 * J], gv[4 * J], ev[4 * J];
#pragma unroll
  for (int j = 0; j < J; ++j) {
    *reinterpret_cast<f32x4*>(bv + 4 * j) = *reinterpret_cast<const f32x4*>(par + cb + 64 * j);
    *reinterpret_cast<f32x4*>(gv + 4 * j) = *reinterpret_cast<const f32x4*>(par + N + cb + 64 * j);
    *reinterpret_cast<f32x4*>(ev + 4 * j) = *reinterpret_cast<const f32x4*>(par + 2 * N + cb + 64 * j);
  }
  float s1 = 0.f, s2 = 0.f;
#pragma unroll
  for (int e = 0; e < 4 * J; ++e) {
    y[e] += bv[e];
    s1 += y[e]; s2 = __builtin_fmaf(y[e], y[e], s2);
  }
  s1 = red16(s1); s2 = red16(s2);
  const float mu = s1 * (1.0f / N);
  const float var = s2 * (1.0f / N) - mu * mu;
  const float rstd = rsqrtf(var + 1e-5f);
  const float nmr = -mu * rstd;
#pragma unroll
  for (int j = 0; j < J; ++j) {
    unsigned int pk[2];
#pragma unroll
    for (int i = 0; i < 4; ++i) {
      const int e = 4 * j + i;
      float t = __builtin_fmaf(y[e], rstd, nmr);
      float o = __builtin_fmaf(t, gv[e], ev[e]);
      float xv;
      if constexpr (MODE == 0) { xv = fmaxf(o, 0.f); xprev[e] = xv; }
      else if constexpr (MODE == 1) { xv = xprev[e] + fmaxf(o, 0.f); xprev[e] = xv; }
      else { xv = o; }
      if (i & 1)
        pk[i >> 1] = __builtin_amdgcn_perm(rne16(xv),
                       rne16(__builtin_bit_cast(float, pk[i >> 1])), 0x07060302);
      else
        pk[i >> 1] = __builtin_bit_cast(unsigned int, xv);
    }
    if constexpr (MODE != 2) {       // b64 store; bank residue 2(2q+l16): uniform
      unsigned int* Xw = reinterpret_cast<unsigned int*>(Xb);
      *reinterpret_cast<uint2*>(Xw + row * 132 + 2 * l16 + 32 * j) =
          *reinterpret_cast<uint2*>(pk);
    } else {                         // head: z -> global Z (8B per j-group)
      *reinterpret_cast<uint2*>(Z + (rowglob + row) * 128 + cb + 64 * j) =
          *reinterpret_cast<uint2*>(pk);
    }
  }
}

// ---------------------------------------------------------------------------
// Kernel 1: ResNetMLP over 64 rows (half graph). 2048 blocks x 1024 thr.
// ---------------------------------------------------------------------------
__global__ __attribute__((amdgpu_flat_work_group_size(1024, 1024), amdgpu_waves_per_eu(4)))
void mlp_main(const float* __restrict__ H, const unsigned short* __restrict__ ws,
              const float* __restrict__ b_in, const float* __restrict__ g_in,
              const float* __restrict__ beta_in,
              const float* __restrict__ bb, const float* __restrict__ gb,
              const float* __restrict__ betab,
              const float* __restrict__ b_out, const float* __restrict__ g_out,
              const float* __restrict__ beta_out,
              unsigned short* __restrict__ Z) {
  extern __shared__ char smem[];
  unsigned short* Xb = (unsigned short*)smem;
  float* Yb = (float*)(smem + LDS_YB);
  float* par = (float*)(smem + LDS_PAR);
  const int tid = threadIdx.x;
  const int wave = tid >> 6, lane = tid & 63;
  const size_t rowglob = (size_t)blockIdx.x * 64;

  // stage H (64 x 64 fp32) -> Xb bf16 ; 4 values/thread, packed b64 store
  {
    int row = tid >> 4, c4 = (tid & 15) * 4;
    float4 f = *reinterpret_cast<const float4*>(H + (rowglob + row) * 64 + c4);
    uint2 o;
    o.x = __builtin_amdgcn_perm(rne16(f.y), rne16(f.x), 0x07060302);
    o.y = __builtin_amdgcn_perm(rne16(f.w), rne16(f.z), 0x07060302);
    *reinterpret_cast<uint2*>(Xb + row * XB_STRIDE + c4) = o;
  }

  float xprev[16];
  layer<64, 256, 0>(Xb, Yb, par, ws,           tid, wave, lane, b_in,     g_in,     beta_in,  xprev, Z, rowglob);
  layer<256, 256, 1>(Xb, Yb, par, ws + 16384,  tid, wave, lane, bb,       gb,       betab,    xprev, Z, rowglob);
  layer<256, 256, 1>(Xb, Yb, par, ws + 81920,  tid, wave, lane, bb + 256, gb + 256, betab + 256, xprev, Z, rowglob);
  layer<256, 256, 1>(Xb, Yb, par, ws + 147456, tid, wave, lane, bb + 512, gb + 512, betab + 512, xprev, Z, rowglob);
  layer<256, 128, 2>(Xb, Yb, par, ws + 212992, tid, wave, lane, b_out,    g_out,    beta_out, xprev, Z, rowglob);
}

// ---------------------------------------------------------------------------
// Kernel 2: per-graph gram + mean-distance + softmax + weighted pool.
// 1024 blocks x 512 thr; Z[g] (128x128 bf16) staged to LDS. (R7-verified.)
// ---------------------------------------------------------------------------
__global__ __attribute__((amdgpu_flat_work_group_size(512, 512)))
void pool_main(const unsigned short* __restrict__ Z, float* __restrict__ out) {
  __shared__ unsigned short Zb[128 * ZB_STRIDE];
  __shared__ float sqv[128], sm[128], smw[128];
  const int tid = threadIdx.x;
  const int g = blockIdx.x;
  const int wave = tid >> 6, lane = tid & 63;
  const int q = lane >> 4, l16 = lane & 15;

  {
    int zr = tid >> 2, zc = (tid & 3) * 32;
    const uint4* zp = reinterpret_cast<const uint4*>(Z + ((size_t)g * 128 + zr) * 128 + zc);
    uint4* zd = reinterpret_cast<uint4*>(Zb + zr * ZB_STRIDE + zc);
    zd[0] = zp[0]; zd[1] = zp[1]; zd[2] = zp[2]; zd[3] = zp[3];
  }
  __syncthreads();

  // gram G = Z Z^T : wave owns 16 rows x 128 cols
  f32x4 g2[8];
#pragma unroll
  for (int nt = 0; nt < 8; ++nt) g2[nt] = zero4();
#pragma unroll
  for (int ks = 0; ks < 4; ++ks) {
    int kk = ks * 32 + q * 8;
    bf16x8 a = *reinterpret_cast<const bf16x8*>(Zb + (16 * wave + l16) * ZB_STRIDE + kk);
#pragma unroll
    for (int nt = 0; nt < 8; ++nt) {
      bf16x8 bfr = *reinterpret_cast<const bf16x8*>(Zb + (16 * nt + l16) * ZB_STRIDE + kk);
      g2[nt] = __builtin_amdgcn_mfma_f32_16x16x32_bf16(a, bfr, g2[nt], 0, 0, 0);
    }
  }
  // publish sq_i = G_ii (diag) so d_ii == sqrt(1e-12) exactly like ref
  if ((l16 >> 2) == q) {
#pragma unroll
    for (int nt = 0; nt < 8; ++nt)
      if (nt == wave) {
#pragma unroll
        for (int r = 0; r < 4; ++r)
          if ((l16 & 3) == r) sqv[16 * wave + l16] = g2[nt][r];
      }
  }
  __syncthreads();
  // distances and s_i = mean_j d_ij
  float sqi[4];
#pragma unroll
  for (int r = 0; r < 4; ++r) sqi[r] = sqv[16 * wave + q * 4 + r];
  float sp[4] = {0.f, 0.f, 0.f, 0.f};
#pragma unroll
  for (int nt = 0; nt < 8; ++nt) {
    float sqj = sqv[16 * nt + l16];
#pragma unroll
    for (int r = 0; r < 4; ++r) {
      float d2 = sqi[r] + sqj - 2.0f * g2[nt][r];
      sp[r] += sqrtf(fmaxf(d2, 0.f) + 1e-12f);
    }
  }
#pragma unroll
  for (int d = 1; d < 16; d <<= 1) {
#pragma unroll
    for (int r = 0; r < 4; ++r) { float t = sp[r]; t += __shfl_xor(t, d); sp[r] = t; }
  }
  if (l16 == 0) {
#pragma unroll
    for (int r = 0; r < 4; ++r) sm[16 * wave + q * 4 + r] = sp[r] * (1.0f / 128.0f);
  }
  __syncthreads();
  // softmax(s/TAU) by wave 0 (1/TAU = 4)
  if (wave == 0) {
    float l0 = sm[lane] * 4.0f;
    float l1 = sm[lane + 64] * 4.0f;
    float mx = fmaxf(l0, l1);
#pragma unroll
    for (int d = 1; d < 64; d <<= 1) mx = fmaxf(mx, __shfl_xor(mx, d));
    float e0 = __expf(l0 - mx), e1 = __expf(l1 - mx);
    float ss = e0 + e1;
#pragma unroll
    for (int d = 1; d < 64; d <<= 1) ss += __shfl_xor(ss, d);
    float inv = 1.0f / ss;
    float w0 = e0 * inv, w1 = e1 * inv;
    smw[lane] = w0;
    smw[lane + 64] = w1;
    out[131072 + g * 128 + lane] = w0;
    out[131072 + g * 128 + 64 + lane] = w1;
  }
  __syncthreads();
  // v_loc = sum_i w_i * Z[i,:]
  {
    int c = 16 * wave + l16;
    float acv = 0.f;
#pragma unroll
    for (int i0 = 0; i0 < 32; ++i0) {
      int i = q * 32 + i0;
      acv += smw[i] * bf2f(Zb[i * ZB_STRIDE + c]);
    }
    acv += __shfl_xor(acv, 16);
    acv += __shfl_xor(acv, 32);
    if (q == 0) out[g * 128 + c] = acv;
  }
}

// ---------------------------------------------------------------------------
extern "C" void kernel_launch(void* const* d_in, const int* in_sizes, int n_in,
                              void* d_out, int out_size, void* d_ws, size_t ws_size,
                              hipStream_t stream) {
  (void)in_sizes; (void)n_in; (void)out_size; (void)ws_size;
  const float* H        = (const float*)d_in[0];
  // d_in[1] = batch_ptr (uniform 128/graph, unused)
  const float* W_in     = (const float*)d_in[2];
  const float* b_in     = (const float*)d_in[3];
  const float* g_in     = (const float*)d_in[4];
  const float* beta_in  = (const float*)d_in[5];
  const float* Wb       = (const float*)d_in[6];
  const float* bb       = (const float*)d_in[7];
  const float* gb       = (const float*)d_in[8];
  const float* betab    = (const float*)d_in[9];
  const float* W_out    = (const float*)d_in[10];
  const float* b_out    = (const float*)d_in[11];
  const float* g_out    = (const float*)d_in[12];
  const float* beta_out = (const float*)d_in[13];
  float* out = (float*)d_out;
  unsigned short* ws = (unsigned short*)d_ws;
  unsigned short* Z = ws + 262144;      // 1024*128*128 bf16 = 33.5 MB

  prep_weights<<<960, 256, 0, stream>>>(W_in, Wb, W_out, ws);
  hipFuncSetAttribute(reinterpret_cast<const void*>(mlp_main),
                      hipFuncAttributeMaxDynamicSharedMemorySize, LDS_TOTAL);
  mlp_main<<<2048, 1024, LDS_TOTAL, stream>>>(H, ws, b_in, g_in, beta_in,
                                              bb, gb, betab, b_out, g_out, beta_out, Z);
  pool_main<<<1024, 512, 0, stream>>>(Z, out);
}